// Round 13
// baseline (116.032 us; speedup 1.0000x reference)
//
#include <hip/hip_runtime.h>
#include <math.h>

#define S 4096
#define B 16
#define QT 1024         // K-quarter width
#define R 8             // attention rows per wave

// ---------------------------------------------------------------------------
// QKV stage 1: partial GEMM over one K-quarter. x[16][1024] lives in LDS
// (loaded ONCE per block — zero steady-state barriers); W is the only global
// stream, probe-shaped: per window, 3 independent 1KB row loads consumed by
// LDS-fed FMAs. W read exactly once from HBM chip-wide. Wave handles 12
// row-quarters as 4 triples; per row: butterfly-reduce 16 partials, write to
// pbuf[qtr][rr][16]. Grid 512 blocks x 512 thr (8 waves), 64KB LDS ->
// 2 blocks/CU, 16 waves/CU; in-flight ~3KB x 16 waves ~= 48KB/CU.
// ---------------------------------------------------------------------------
__global__ __launch_bounds__(512, 4) void qkv_partial(
    const float* __restrict__ x,
    const float* __restrict__ Wq, const float* __restrict__ Wk,
    const float* __restrict__ Wv, float* __restrict__ pbuf)
{
    __shared__ float xs[B][QT];      // 64 KB
    const int tid   = threadIdx.x;
    const int lane  = tid & 63;
    const int wave  = tid >> 6;      // 0..7
    const int bx    = blockIdx.x;    // 0..511
    const int qtr   = bx & 3;        // K-quarter
    const int chunk = bx >> 2;       // 0..127

    // stage x quarter: 4096 float4s, 8 per thread, coalesced
    #pragma unroll
    for (int i = 0; i < 8; ++i) {
        const int f  = tid + i * 512;
        const int b  = f >> 8;           // 256 float4 per batch row
        const int c4 = f & 255;
        *(float4*)&xs[b][c4 * 4] =
            *(const float4*)&x[(size_t)b * S + qtr * QT + c4 * 4];
    }
    __syncthreads();                     // the ONLY barrier

    #pragma unroll 1
    for (int t3 = 0; t3 < 4; ++t3) {
        const int rr0 = chunk * 96 + wave * 12 + t3 * 3;  // row-task triple
        const int rrA = rr0, rrB = rr0 + 1, rrC = rr0 + 2;
        const int mA = rrA >> 12, mB = rrB >> 12, mC = rrC >> 12;
        const float* WA = (mA == 0) ? Wq : (mA == 1) ? Wk : Wv;
        const float* WB = (mB == 0) ? Wq : (mB == 1) ? Wk : Wv;
        const float* WC = (mC == 0) ? Wq : (mC == 1) ? Wk : Wv;
        const float* wpA = WA + (size_t)(rrA & 4095) * S + qtr * QT + lane * 4;
        const float* wpB = WB + (size_t)(rrB & 4095) * S + qtr * QT + lane * 4;
        const float* wpC = WC + (size_t)(rrC & 4095) * S + qtr * QT + lane * 4;

        float p0[16], p1[16], p2[16];
        #pragma unroll
        for (int b = 0; b < 16; ++b) { p0[b] = 0.f; p1[b] = 0.f; p2[b] = 0.f; }

        #pragma unroll 2
        for (int win = 0; win < 4; ++win) {
            const int off = win * 256;
            float4 wa = *(const float4*)&wpA[off];
            float4 wb = *(const float4*)&wpB[off];
            float4 wc = *(const float4*)&wpC[off];
            #pragma unroll
            for (int b = 0; b < 16; ++b) {
                float4 xv = *(const float4*)&xs[b][off + lane * 4];
                p0[b] = fmaf(wa.x, xv.x, p0[b]);
                p0[b] = fmaf(wa.y, xv.y, p0[b]);
                p0[b] = fmaf(wa.z, xv.z, p0[b]);
                p0[b] = fmaf(wa.w, xv.w, p0[b]);
                p1[b] = fmaf(wb.x, xv.x, p1[b]);
                p1[b] = fmaf(wb.y, xv.y, p1[b]);
                p1[b] = fmaf(wb.z, xv.z, p1[b]);
                p1[b] = fmaf(wb.w, xv.w, p1[b]);
                p2[b] = fmaf(wc.x, xv.x, p2[b]);
                p2[b] = fmaf(wc.y, xv.y, p2[b]);
                p2[b] = fmaf(wc.z, xv.z, p2[b]);
                p2[b] = fmaf(wc.w, xv.w, p2[b]);
            }
        }

        // butterfly-reduce each partial across 64 lanes; lane b writes b
        #define REDUCE_ROW(parr, rr)                                         \
        {                                                                    \
            _Pragma("unroll")                                                \
            for (int b = 0; b < 16; ++b) {                                   \
                float s = parr[b];                                           \
                s += __shfl_xor(s,  1, 64);                                  \
                s += __shfl_xor(s,  2, 64);                                  \
                s += __shfl_xor(s,  4, 64);                                  \
                s += __shfl_xor(s,  8, 64);                                  \
                s += __shfl_xor(s, 16, 64);                                  \
                s += __shfl_xor(s, 32, 64);                                  \
                parr[b] = s;                                                 \
            }                                                                \
            float v = parr[0];                                               \
            _Pragma("unroll")                                                \
            for (int b = 1; b < 16; ++b) v = (lane == b) ? parr[b] : v;      \
            if (lane < 16)                                                   \
                pbuf[((size_t)qtr * 12288 + (rr)) * 16 + lane] = v;          \
        }
        REDUCE_ROW(p0, rrA)
        REDUCE_ROW(p1, rrB)
        REDUCE_ROW(p2, rrC)
        #undef REDUCE_ROW
    }
}

// ---------------------------------------------------------------------------
// QKV stage 2: sum the 4 K-quarter partials + bias -> q/k/v.
// 196608 outputs = 3 mats x 16 batches x 4096 rows -> 768 blocks x 256.
// (R12 bug: launched 3072 blocks = 786432 threads; idx>=196608 decoded
// mat=3..11, read pbuf far OOB and overwrote v with garbage.)
// ---------------------------------------------------------------------------
__global__ __launch_bounds__(256) void combine_kernel(
    const float* __restrict__ pbuf,
    const float* __restrict__ bq, const float* __restrict__ bk,
    const float* __restrict__ bv,
    float* __restrict__ q, float* __restrict__ k, float* __restrict__ v)
{
    const int idx = blockIdx.x * 256 + threadIdx.x;   // 0..196607
    const int mat = idx >> 16;                        // 0..2
    const int b   = (idx >> 12) & 15;
    const int row = idx & 4095;
    const int rr  = mat * 4096 + row;
    float s = pbuf[((size_t)0 * 12288 + rr) * 16 + b]
            + pbuf[((size_t)1 * 12288 + rr) * 16 + b]
            + pbuf[((size_t)2 * 12288 + rr) * 16 + b]
            + pbuf[((size_t)3 * 12288 + rr) * 16 + b];
    const float* bias = (mat == 0) ? bq : (mat == 1) ? bk : bv;
    float*       out  = (mat == 0) ? q  : (mat == 1) ? k  : v;
    out[(size_t)b * S + row] = s + bias[row];
}

// ---------------------------------------------------------------------------
// Inclusive prefix max/min of k per batch row. 16 blocks x 256 threads.
// ---------------------------------------------------------------------------
__global__ __launch_bounds__(256) void scan_kernel(
    const float* __restrict__ k,
    float* __restrict__ rmax, float* __restrict__ rmin)
{
    __shared__ float smax[256], smin[256];
    const int b = blockIdx.x, t = threadIdx.x;
    const float* kb = k + b * S;

    float seg[16];
    float lmax = -INFINITY, lmin = INFINITY;
    #pragma unroll
    for (int e = 0; e < 16; ++e) {
        seg[e] = kb[t * 16 + e];
        lmax = fmaxf(lmax, seg[e]);
        lmin = fminf(lmin, seg[e]);
    }
    smax[t] = lmax; smin[t] = lmin;
    __syncthreads();
    for (int off = 1; off < 256; off <<= 1) {
        float vx = (t >= off) ? smax[t - off] : -INFINITY;
        float vn = (t >= off) ? smin[t - off] :  INFINITY;
        __syncthreads();
        smax[t] = fmaxf(smax[t], vx);
        smin[t] = fminf(smin[t], vn);
        __syncthreads();
    }
    float runmax = (t > 0) ? smax[t - 1] : -INFINITY;
    float runmin = (t > 0) ? smin[t - 1] :  INFINITY;
    #pragma unroll
    for (int e = 0; e < 16; ++e) {
        runmax = fmaxf(runmax, seg[e]);
        runmin = fminf(runmin, seg[e]);
        rmax[b * S + t * 16 + e] = runmax;
        rmin[b * S + t * 16 + e] = runmin;
    }
}

// ---------------------------------------------------------------------------
// d=1 causal attention, single pass (row max known from prefix scan).
// Wave handles R=8 consecutive rows of one batch, sharing k/v loads.
// ---------------------------------------------------------------------------
__global__ __launch_bounds__(256) void attn_kernel(
    const float* __restrict__ q, const float* __restrict__ k,
    const float* __restrict__ v,
    const float* __restrict__ rmax, const float* __restrict__ rmin,
    float* __restrict__ out)
{
    const int tid = threadIdx.x, lane = tid & 63, wave = tid >> 6;
    const int task = blockIdx.x * 4 + wave;     // 0..8191
    const int b    = task & 15;
    const int rbi  = task >> 4;                 // 0..511
    const int i0   = (511 - rbi) * R;           // descending: big rows first
    const float* kb = k + b * S;
    const float* vb = v + b * S;
    const float LOG2E = 1.4426950408889634f;

    float a[R], cc[R], den[R], num[R];
    #pragma unroll
    for (int r = 0; r < R; ++r) {
        float qi = q[b * S + i0 + r];
        float m  = (qi >= 0.f) ? qi * rmax[b * S + i0 + r]
                               : qi * rmin[b * S + i0 + r];
        a[r]  = qi * LOG2E;
        cc[r] = -m * LOG2E;
        den[r] = 0.f; num[r] = 0.f;
    }

    const int nfull = (i0 + 1) >> 8;            // full 256-wide chunks
    #pragma unroll 1
    for (int it = 0; it < nfull; ++it) {
        const int j = it * 256 + lane * 4;
        float4 k4 = *(const float4*)&kb[j];
        float4 v4 = *(const float4*)&vb[j];
        #pragma unroll
        for (int jj = 0; jj < 4; ++jj) {
            float kx = (&k4.x)[jj], vx = (&v4.x)[jj];
            #pragma unroll
            for (int r = 0; r < R; ++r) {
                float e = exp2f(fmaf(a[r], kx, cc[r]));
                den[r] += e;
                num[r] = fmaf(e, vx, num[r]);
            }
        }
    }
    // masked tail
    const int imax = i0 + R - 1;
    for (int j = nfull * 256 + lane; j <= imax; j += 64) {
        float kx = kb[j], vx = vb[j];
        #pragma unroll
        for (int r = 0; r < R; ++r) {
            float e = (j <= i0 + r) ? exp2f(fmaf(a[r], kx, cc[r])) : 0.f;
            den[r] += e;
            num[r] = fmaf(e, vx, num[r]);
        }
    }

    #pragma unroll
    for (int r = 0; r < R; ++r) {
        float d = den[r], n = num[r];
        #pragma unroll
        for (int off = 32; off; off >>= 1) {
            d += __shfl_xor(d, off, 64);
            n += __shfl_xor(n, off, 64);
        }
        if (lane == r) out[b * S + i0 + r] = n / d;
    }
}

extern "C" void kernel_launch(void* const* d_in, const int* in_sizes, int n_in,
                              void* d_out, int out_size, void* d_ws, size_t ws_size,
                              hipStream_t stream) {
    const float* x  = (const float*)d_in[0];
    const float* Wq = (const float*)d_in[1];
    const float* bq = (const float*)d_in[2];
    const float* Wk = (const float*)d_in[3];
    const float* bk = (const float*)d_in[4];
    const float* Wv = (const float*)d_in[5];
    const float* bv = (const float*)d_in[6];
    float* out = (float*)d_out;

    float* ws   = (float*)d_ws;
    float* q    = ws;                // 16*4096
    float* k    = ws + 65536;
    float* v    = ws + 131072;
    float* rmax = ws + 196608;
    float* rmin = ws + 262144;
    float* pbuf = ws + 327680;       // 4*12288*16 = 786432 floats (3 MB)

    qkv_partial<<<512, 512, 0, stream>>>(x, Wq, Wk, Wv, pbuf);
    combine_kernel<<<768, 256, 0, stream>>>(pbuf, bq, bk, bv, q, k, v);
    scan_kernel<<<16, 256, 0, stream>>>(k, rmax, rmin);
    attn_kernel<<<2048, 256, 0, stream>>>(q, k, v, rmax, rmin, out);
}